// Round 4
// baseline (909.955 us; speedup 1.0000x reference)
//
#include <hip/hip_runtime.h>
#include <hip/hip_bf16.h>
#include <stdint.h>

// x:[32,2048,512] f32  W*:[512,512] f32  b*:[512] f32  factor:[1,64,256,8] f32
// out f32 [32,2048,512].
//
// Pipeline:
//   cast x->bf16, Wq->bf16
//   gprep: G_k/G_v[a][half][r][d] = sum_j W[half*256+j][d]*f[a][j][r]  (+bias c)
//   qgemm: Q = xb @ Wq^T + bq  (bf16 MFMA, 34 GFLOP)
//   k2v2:  k2/v2[b][a][h][r] = dot(x_row, G[a][h&1][r][:]) + c   (fp32 VALU)
//   attn:  scores = q^T k2 /8, softmax(8), out = p @ v2^T  (LDS-staged Q)

typedef unsigned short ushort_t;

using bf16x8 = __attribute__((ext_vector_type(8))) short;
using f32x4  = __attribute__((ext_vector_type(4))) float;

__device__ __forceinline__ float bf2f(unsigned short u) {
  union { unsigned int i; float f; } v;
  v.i = ((unsigned int)u) << 16;
  return v.f;
}
__device__ __forceinline__ unsigned short f2bf(float f) {
  __hip_bfloat16 h = __float2bfloat16(f);
  return *reinterpret_cast<unsigned short*>(&h);
}

__device__ __forceinline__ void load_lds16(const void* g, void* l) {
  __builtin_amdgcn_global_load_lds(
      (const __attribute__((address_space(1))) unsigned int*)g,
      (__attribute__((address_space(3))) unsigned int*)l,
      16, 0, 0);
}

// ---------------------------------------------------------------------------
// fp32 -> bf16 cast, 4 elems/thread
// ---------------------------------------------------------------------------
__global__ __launch_bounds__(256)
void cast_f32_bf16(const float* __restrict__ src, ushort_t* __restrict__ dst,
                   int n4) {
  int i = blockIdx.x * blockDim.x + threadIdx.x;
  if (i < n4) {
    float4 v = ((const float4*)src)[i];
    ushort_t p[4] = {f2bf(v.x), f2bf(v.y), f2bf(v.z), f2bf(v.w)};
    *(uint2*)(dst + 4 * (size_t)i) = *(const uint2*)p;
  }
}

// ---------------------------------------------------------------------------
// gprep: grid (a=64, half=2, mat=2), block 512 (thread=d).
// G[a][half][r][d] (fp32) and c[a][half][r].
// ---------------------------------------------------------------------------
__global__ __launch_bounds__(512)
void gprep(const float* __restrict__ Wk, const float* __restrict__ bk,
           const float* __restrict__ Wv, const float* __restrict__ bv,
           const float* __restrict__ F,
           float* __restrict__ Gk, float* __restrict__ Gv,
           float* __restrict__ ck, float* __restrict__ cv) {
  const int a = blockIdx.x, half = blockIdx.y, mat = blockIdx.z;
  const int d = threadIdx.x;
  const float* W = mat ? Wv : Wk;
  const float* B = mat ? bv : bk;
  float* G = mat ? Gv : Gk;
  float* C = mat ? cv : ck;

  float acc[8];
#pragma unroll
  for (int r = 0; r < 8; ++r) acc[r] = 0.f;

  const float* Fb = F + (size_t)a * 2048;
  for (int j = 0; j < 256; ++j) {
    const float w = W[(size_t)(half * 256 + j) * 512 + d];  // coalesced over d
    float4 f0 = *(const float4*)(Fb + j * 8);
    float4 f1 = *(const float4*)(Fb + j * 8 + 4);
    acc[0] += w * f0.x; acc[1] += w * f0.y;
    acc[2] += w * f0.z; acc[3] += w * f0.w;
    acc[4] += w * f1.x; acc[5] += w * f1.y;
    acc[6] += w * f1.z; acc[7] += w * f1.w;
  }
  const size_t gbase = (size_t)((a * 2 + half) * 8) * 512;
#pragma unroll
  for (int r = 0; r < 8; ++r) G[gbase + (size_t)r * 512 + d] = acc[r];

  if (d < 8) {  // bias contraction: c[r=d]
    float cb = 0.f;
    for (int j = 0; j < 256; ++j)
      cb += B[half * 256 + j] * Fb[j * 8 + d];
    C[(a * 2 + half) * 8 + d] = cb;
  }
}

// ---------------------------------------------------------------------------
// qgemm: C[M=65536,512] = xb[M,512] @ Wq[512,512]^T + bq. grid (4, 512).
// ---------------------------------------------------------------------------
__global__ __launch_bounds__(256)
void qgemm(const ushort_t* __restrict__ X, const ushort_t* __restrict__ W,
           const float* __restrict__ Bi, ushort_t* __restrict__ O) {
  __shared__ __align__(16) short sA[128 * 32];
  __shared__ __align__(16) short sB[128 * 32];

  const int tid  = threadIdx.x;
  const int lane = tid & 63;
  const int wid  = tid >> 6;
  const int m0 = blockIdx.y * 128;
  const int n0 = blockIdx.x * 128;
  const int wave_m = (wid & 1) * 64;
  const int wave_n = (wid >> 1) * 64;
  const int quad = lane >> 4;
  const int l15  = lane & 15;

  f32x4 acc[4][4];
#pragma unroll
  for (int i = 0; i < 4; ++i)
#pragma unroll
    for (int j = 0; j < 4; ++j) acc[i][j] = f32x4{0.f, 0.f, 0.f, 0.f};

  const int s0 = wid * 128 + lane;
  const int s1 = s0 + 64;
  short* ldsA0 = &sA[(wid * 128) * 8];
  short* ldsA1 = &sA[(wid * 128 + 64) * 8];
  short* ldsB0 = &sB[(wid * 128) * 8];
  short* ldsB1 = &sB[(wid * 128 + 64) * 8];

  for (int kt = 0; kt < 512; kt += 32) {
    const ushort_t* ga0 = X + ((size_t)(m0 + (s0 >> 2)) << 9) + kt + (s0 & 3) * 8;
    const ushort_t* ga1 = X + ((size_t)(m0 + (s1 >> 2)) << 9) + kt + (s1 & 3) * 8;
    const ushort_t* gb0 = W + ((size_t)(n0 + (s0 >> 2)) << 9) + kt + (s0 & 3) * 8;
    const ushort_t* gb1 = W + ((size_t)(n0 + (s1 >> 2)) << 9) + kt + (s1 & 3) * 8;
    load_lds16(ga0, ldsA0);
    load_lds16(ga1, ldsA1);
    load_lds16(gb0, ldsB0);
    load_lds16(gb1, ldsB1);
    __syncthreads();

    bf16x8 af[4], bfr[4];
#pragma unroll
    for (int i = 0; i < 4; ++i)
      af[i] = *(const bf16x8*)&sA[(wave_m + i * 16 + l15) * 32 + quad * 8];
#pragma unroll
    for (int j = 0; j < 4; ++j)
      bfr[j] = *(const bf16x8*)&sB[(wave_n + j * 16 + l15) * 32 + quad * 8];
#pragma unroll
    for (int i = 0; i < 4; ++i)
#pragma unroll
      for (int j = 0; j < 4; ++j)
        acc[i][j] = __builtin_amdgcn_mfma_f32_16x16x32_bf16(af[i], bfr[j],
                                                            acc[i][j], 0, 0, 0);
    __syncthreads();
  }

  // C/D layout: col=lane&15, row=(lane>>4)*4+reg  [verified m89/m91]
#pragma unroll
  for (int j = 0; j < 4; ++j) {
    const int gn = n0 + wave_n + j * 16 + l15;
    const float bv = Bi[gn];
#pragma unroll
    for (int i = 0; i < 4; ++i) {
      const int gmBase = m0 + wave_m + i * 16 + quad * 4;
      f32x4 c = acc[i][j];
#pragma unroll
      for (int rg = 0; rg < 4; ++rg)
        O[((size_t)(gmBase + rg) << 9) + gn] = f2bf(c[rg] + bv);
    }
  }
}

// ---------------------------------------------------------------------------
// k2v2: grid (a=64, b=32), block 256. thread t -> h=t>>2, r0=(t&3)*2.
// k2[b][a][h][r] = dot(x[l], Gk[a][h&1][r][:]) + ck ;  same for v2.
// ---------------------------------------------------------------------------
__global__ __launch_bounds__(256)
void k2v2_ker(const float* __restrict__ x,
              const float* __restrict__ Gk, const float* __restrict__ Gv,
              const float* __restrict__ ck, const float* __restrict__ cv,
              float* __restrict__ K2, float* __restrict__ V2) {
  const int a = blockIdx.x, b = blockIdx.y, t = threadIdx.x;
  const int h = t >> 2;
  const int r0 = (t & 3) * 2;
  const int half = h & 1;

  const float* xr = x + ((size_t)(b * 2048 + a * 32 + (h >> 1)) << 9);
  const size_t gb = ((size_t)((a * 2 + half) * 8 + r0)) << 9;
  const float* gk0 = Gk + gb;
  const float* gk1 = gk0 + 512;
  const float* gv0 = Gv + gb;
  const float* gv1 = gv0 + 512;

  float ak0 = 0.f, ak1 = 0.f, av0 = 0.f, av1 = 0.f;
  for (int d = 0; d < 512; d += 4) {
    float4 xv = *(const float4*)(xr + d);
    float4 k0 = *(const float4*)(gk0 + d);
    float4 k1 = *(const float4*)(gk1 + d);
    float4 v0 = *(const float4*)(gv0 + d);
    float4 v1 = *(const float4*)(gv1 + d);
    ak0 += xv.x * k0.x + xv.y * k0.y + xv.z * k0.z + xv.w * k0.w;
    ak1 += xv.x * k1.x + xv.y * k1.y + xv.z * k1.z + xv.w * k1.w;
    av0 += xv.x * v0.x + xv.y * v0.y + xv.z * v0.z + xv.w * v0.w;
    av1 += xv.x * v1.x + xv.y * v1.y + xv.z * v1.z + xv.w * v1.w;
  }
  const int cbase = (a * 2 + half) * 8 + r0;
  const size_t ob = ((size_t)((b * 64 + a) * 64 + h) << 3) + r0;
  float2 kk = {ak0 + ck[cbase], ak1 + ck[cbase + 1]};
  float2 vv = {av0 + cv[cbase], av1 + cv[cbase + 1]};
  *(float2*)(K2 + ob) = kk;
  *(float2*)(V2 + ob) = vv;
}

// ---------------------------------------------------------------------------
// attn: grid (a=64, b=32), block 256 (thread = lr).
// ---------------------------------------------------------------------------
__global__ __launch_bounds__(256)
void attn_bc(const ushort_t* __restrict__ Q, const float* __restrict__ K2,
             const float* __restrict__ V2, float* __restrict__ Out) {
  const int a = blockIdx.x, b = blockIdx.y, t = threadIdx.x;
  const int lane = t & 63, wid = t >> 6;

  __shared__ __align__(16) ushort_t sQ[32 * 512];  // 32 KB
  __shared__ __align__(16) float sK2[512];         // [h*8+r]
  __shared__ __align__(16) float sV2[512];

  const ushort_t* Qs = Q + ((size_t)(b * 2048 + a * 32) << 9);  // contiguous 32KB
  const float* k2s = K2 + ((size_t)(b * 64 + a) << 9);
  const float* v2s = V2 + ((size_t)(b * 64 + a) << 9);

  // stage Q: 2048 x 16B segs; wave w covers segs [w*512, +512)
#pragma unroll
  for (int i = 0; i < 8; ++i) {
    const int seg = wid * 512 + i * 64 + lane;
    load_lds16(Qs + (size_t)seg * 8, sQ + (size_t)seg * 8);
  }
  {  // k2/v2: 128 segs each; waves 0-1 -> k2, waves 2-3 -> v2
    const int seg = (wid & 1) * 64 + lane;
    if (wid < 2) load_lds16(k2s + seg * 4, sK2 + seg * 4);
    else         load_lds16(v2s + seg * 4, sV2 + seg * 4);
  }
  __syncthreads();

  const int lr = t;
  float s[8];
#pragma unroll
  for (int r = 0; r < 8; ++r) s[r] = 0.f;

  for (int h = 0; h < 64; ++h) {
    const float qv = bf2f(sQ[(h >> 1) * 512 + (h & 1) * 256 + lr]);
    float4 ka = *(const float4*)&sK2[h * 8];      // wave-uniform -> broadcast
    float4 kb = *(const float4*)&sK2[h * 8 + 4];
    s[0] += qv * ka.x; s[1] += qv * ka.y; s[2] += qv * ka.z; s[3] += qv * ka.w;
    s[4] += qv * kb.x; s[5] += qv * kb.y; s[6] += qv * kb.z; s[7] += qv * kb.w;
  }

  float mx = -1e30f;
#pragma unroll
  for (int r = 0; r < 8; ++r) { s[r] *= 0.125f; mx = fmaxf(mx, s[r]); }
  float sum = 0.f;
#pragma unroll
  for (int r = 0; r < 8; ++r) { s[r] = __expf(s[r] - mx); sum += s[r]; }
  const float inv = 1.0f / sum;
#pragma unroll
  for (int r = 0; r < 8; ++r) s[r] *= inv;

  const size_t obase =
      (((size_t)(b * 2048 + a * 32 + (lr >> 3))) << 9) + (lr & 7) * 64;
  for (int h0 = 0; h0 < 64; h0 += 4) {
    float4 o;
    float* op = (float*)&o;
#pragma unroll
    for (int j = 0; j < 4; ++j) {
      const int h = h0 + j;
      float4 va = *(const float4*)&sV2[h * 8];
      float4 vb = *(const float4*)&sV2[h * 8 + 4];
      op[j] = s[0] * va.x + s[1] * va.y + s[2] * va.z + s[3] * va.w +
              s[4] * vb.x + s[5] * vb.y + s[6] * vb.z + s[7] * vb.w;
    }
    *(float4*)(Out + obase + h0) = o;
  }
}

// ---------------------------------------------------------------------------
extern "C" void kernel_launch(void* const* d_in, const int* in_sizes, int n_in,
                              void* d_out, int out_size, void* d_ws,
                              size_t ws_size, hipStream_t stream) {
  const float* x  = (const float*)d_in[0];
  const float* Wq = (const float*)d_in[1];
  const float* bq = (const float*)d_in[2];
  const float* Wk = (const float*)d_in[3];
  const float* bk = (const float*)d_in[4];
  const float* Wv = (const float*)d_in[5];
  const float* bv = (const float*)d_in[6];
  const float* f  = (const float*)d_in[7];
  float* out = (float*)d_out;

  // ws layout:
  //   xb  bf16 33,554,432        (67 MB)
  //   wqb bf16 262,144           (0.5 MB)
  //   Qb  bf16 33,554,432        (67 MB)
  //   Gk,Gv fp32 524,288 each    (2 MB each)
  //   ck,cv fp32 1024 each
  //   K2,V2 fp32 1,048,576 each  (4 MB each)
  ushort_t* xb  = (ushort_t*)d_ws;
  ushort_t* wqb = xb + 33554432u;
  ushort_t* Qb  = wqb + 262144u;
  float* Gk = (float*)(Qb + 33554432u);
  float* Gv = Gk + 524288u;
  float* ck = Gv + 524288u;
  float* cv = ck + 1024u;
  float* K2 = cv + 1024u;
  float* V2 = K2 + 1048576u;

  cast_f32_bf16<<<32768, 256, 0, stream>>>(x, xb, 33554432 / 4);
  cast_f32_bf16<<<256, 256, 0, stream>>>(Wq, wqb, 262144 / 4);

  dim3 gg(64, 2, 2);
  gprep<<<gg, 512, 0, stream>>>(Wk, bk, Wv, bv, f, Gk, Gv, ck, cv);

  dim3 g1(4, 512);
  qgemm<<<g1, 256, 0, stream>>>(xb, wqb, bq, Qb);

  dim3 g2(64, 32);
  k2v2_ker<<<g2, 256, 0, stream>>>(x, Gk, Gv, ck, cv, K2, V2);

  attn_bc<<<g2, 256, 0, stream>>>(Qb, K2, V2, out);
}